// Round 3
// baseline (1301.543 us; speedup 1.0000x reference)
//
#include <hip/hip_runtime.h>
#include <math.h>

// BWNet scan v4: latency-optimized persistent kernel.
// Tagged-word exchange (data IS the barrier), 2 exchanges/step.
// v4 vs v3:
//  - ALL in-loop barriers are raw "s_waitcnt lgkmcnt(0); s_barrier" (LDS-only
//    drain). No vmcnt(0) drains in the loop -> agent-scope store acks never
//    gate local progress (they hide under the next remote-poll wait).
//  - Phase B reduce: vectorized v4f broadcast LDS loads -> register tree
//    (v3's serial scalar-LDS compare chain removed).
//  - Polls spin hot (no s_sleep; 1 block/CU so spinning is free).
//  - Scan role on blocks with bid%8==0 (XCD co-location heuristic only).

typedef float v4f __attribute__((ext_vector_type(4)));
typedef unsigned long long ull;

#define N_ENT 8192
#define EMB   256
#define KD    32
#define ARD   1024
#define UT    233
#define NSCAN 32
#define NZERO 224
#define NBLK  256

// workspace float-index offsets
#define WS_KEYS 0         // 32*8192 floats, k-major: keys[k*8192+j]
#define WS_C0   262144    // 256: b_a0 + relu(W_fe@um + b_fe)
#define WS_PAIR 262400    // tagged-pair region (byte 1049600, 8B aligned)
#define PR_RI0  0         // 256 pairs: ri0[j], written by scan block j>>3
#define PR_PART 256       // 32 blocks * 40 pairs: [0]=psum [1]=pmax [2]=pidx [3..34]=cand
#define NPAIRS  (256 + 32 * 40)

struct Params {
  const float *um, *emask, *enc, *arin, *W_fe, *b_fe, *W_k, *b_k,
              *W_a0, *b_a0, *W_a1, *b_a1, *W_f, *b_f, *W_i0, *b_i0,
              *W_i1, *b_i1, *W_o, *b_o, *ln_g, *ln_b, *W_a3, *b_a3;
  const int* ct;
  float* out;
  float* wsf;
  int*   wsi;
};

__device__ __forceinline__ ull ld_pair(ull* p_) {
  return __hip_atomic_load(p_, __ATOMIC_RELAXED, __HIP_MEMORY_SCOPE_AGENT);
}
__device__ __forceinline__ void st_pair(ull* p_, ull v) {
  __hip_atomic_store(p_, v, __ATOMIC_RELAXED, __HIP_MEMORY_SCOPE_AGENT);
}
__device__ __forceinline__ ull packf(float v, unsigned tag) {
  return ((ull)tag << 32) | (ull)__float_as_uint(v);
}
__device__ __forceinline__ ull packi(int v, unsigned tag) {
  return ((ull)tag << 32) | (ull)(unsigned)v;
}
__device__ __forceinline__ unsigned ptag(ull u) { return (unsigned)(u >> 32); }
__device__ __forceinline__ float pvalf(ull u) { return __uint_as_float((unsigned)u); }

// LDS-only barrier: drains lgkmcnt (LDS ops) but NOT vmcnt (global stores).
__device__ __forceinline__ void bar_lds() {
  asm volatile("s_waitcnt lgkmcnt(0)\n\ts_barrier" ::: "memory");
}

// ---------------- init: keys GEMM, func_embed, zero tag pairs ----------------
__global__ __launch_bounds__(256) void k_init(Params p) {
  __shared__ float enc_s[32 * 260];
  __shared__ float um_s[UT];
  const int tid = threadIdx.x, bid = blockIdx.x;
  float* keys = p.wsf + WS_KEYS;

  if (bid == 0 && tid < UT) um_s[tid] = p.um[tid];
  if (bid == 3) {  // zero all tag pairs (tag 0 matches no step tag 1..66)
    ull* pr = (ull*)(p.wsf + WS_PAIR);
    for (int i = tid; i < NPAIRS; i += 256) pr[i] = 0ull;
  }

  const int j0 = bid * 32;
  #pragma unroll
  for (int i = 0; i < 8; ++i) {
    int idx = i * 256 + tid;
    int row = idx >> 6, c4 = idx & 63;
    v4f v = *(const v4f*)(p.enc + (size_t)(j0 + row) * EMB + c4 * 4);
    *(v4f*)&enc_s[row * 260 + c4 * 4] = v;
  }
  __syncthreads();
  {
    const int jl = tid >> 3, kg = tid & 7;
    float acc[4];
    #pragma unroll
    for (int kk = 0; kk < 4; ++kk) acc[kk] = p.b_k[kg * 4 + kk];
    for (int e4 = 0; e4 < 64; ++e4) {
      v4f x = *(const v4f*)&enc_s[jl * 260 + e4 * 4];
      #pragma unroll
      for (int kk = 0; kk < 4; ++kk) {
        v4f w = *(const v4f*)(p.W_k + (size_t)(kg * 4 + kk) * EMB + e4 * 4);
        acc[kk] += x.x * w.x + x.y * w.y + x.z * w.z + x.w * w.w;
      }
    }
    const int j = j0 + jl;
    #pragma unroll
    for (int kk = 0; kk < 4; ++kk) keys[(size_t)(kg * 4 + kk) * N_ENT + j] = acc[kk];
  }
  if (bid == 0) {
    float a = p.b_fe[tid];
    const float* wr = p.W_fe + (size_t)tid * UT;
    for (int u = 0; u < UT; ++u) a += wr[u] * um_s[u];
    p.wsf[WS_C0 + tid] = fmaxf(a, 0.f) + p.b_a0[tid];
  }
}

// ---------------- main: scan (bid%8==0) + output zeroing (rest) ----------------
__global__ __launch_bounds__(256, 1) void k_scan(Params p) {
  const int tid = threadIdx.x, bid = blockIdx.x;
  int ctv = p.ct[0];
  const int steps = ctv < 0 ? 0 : (ctv > 64 ? 64 : ctv);
  const size_t NN = (size_t)N_ENT * N_ENT;

  if ((bid & 7) != 0) {  // -------- zero role --------
    const int zid = bid - (bid >> 3) - 1;   // 0..223
    v4f z = (v4f){0.f, 0.f, 0.f, 0.f};
    v4f* o4 = (v4f*)p.out;
    const size_t tot = NN / 4;
    for (size_t i = (size_t)steps * (N_ENT / 4) + (size_t)zid * 256 + tid;
         i < tot; i += (size_t)NZERO * 256)
      __builtin_nontemporal_store(z, o4 + i);
    return;
  }
  const int sid = bid >> 3;  // scan block id 0..31 (all on one XCD if bid%8 maps XCD)

  // -------- scan role --------
  __shared__ float ar_s[32 * 33];
  __shared__ float cand_s[32 * 32];
  __shared__ float ri0_s[8 * 33];
  __shared__ unsigned maskb[256], selb[256];
  __shared__ float x_i1[32], q_s[32], h_s[32], qnf[32];
  __shared__ float garr[128], fog[32], rem[32], og[32];
  __shared__ float b_a1s[32], gb_s[128], lng_s[32], lnb_s[32], c0own[8];
  __shared__ float psums[32], pmaxs[32];
  __shared__ int   pidxs[32];
  __shared__ float reds[4], rmaxs[4];
  __shared__ int   ridxs[4];
  __shared__ int   done_s;

  ull* ri0p  = (ull*)(p.wsf + WS_PAIR) + PR_RI0;
  ull* partp = (ull*)(p.wsf + WS_PAIR) + PR_PART;
  const float* keys = p.wsf + WS_KEYS;

  // ---- preamble: replicated state + weights into LDS / registers ----
  for (int i = tid; i < ARD; i += 256) ar_s[(i >> 5) * 33 + (i & 31)] = p.arin[i];
  {
    unsigned mb = 0u;
    const float* em = p.emask + (size_t)tid * 32;
    #pragma unroll
    for (int j = 0; j < 32; ++j) mb |= (em[j] != 0.f) ? (1u << j) : 0u;
    maskb[tid] = mb; selb[tid] = 0u;
  }
  if (tid < 32) {
    b_a1s[tid] = p.b_a1[tid];
    lng_s[tid] = p.ln_g[tid]; lnb_s[tid] = p.ln_b[tid];
    q_s[tid] = 0.f; h_s[tid] = 0.f; qnf[tid] = 0.f; x_i1[tid] = 0.f;
  }
  if (tid < 128) {
    const int g = tid >> 5, r = tid & 31;
    const float* bg = (g == 0) ? p.b_f : (g == 1) ? p.b_i0 : (g == 2) ? p.b_i1 : p.b_o;
    gb_s[tid] = bg[r];
  }
  if (tid < 8) c0own[tid] = p.wsf[WS_C0 + sid * 8 + tid];
  if (tid == 0) done_s = 0;

  v4f w0[8];  // W_a0 rows [8*sid,8*sid+8): thread = (row tid>>5, cols (tid&31)*32..+32)
  { const float* s = p.W_a0 + (size_t)(sid * 8 + (tid >> 5)) * ARD + (tid & 31) * 32;
    #pragma unroll
    for (int i = 0; i < 8; ++i) w0[i] = ((const v4f*)s)[i]; }
  v4f w1[8];  // W_a1: thread = (row tid>>3, cols (tid&7)*32..+32)
  { const float* s = p.W_a1 + (size_t)(tid >> 3) * EMB + (tid & 7) * 32;
    #pragma unroll
    for (int i = 0; i < 8; ++i) w1[i] = ((const v4f*)s)[i]; }
  v4f wg[8];  // LSTM gates: 128 rows x 2 halves
  { const int rowg = tid >> 1, g = rowg >> 5, r = rowg & 31, half = tid & 1;
    const float* W = (g == 0) ? p.W_f : (g == 1) ? p.W_i0 : (g == 2) ? p.W_i1 : p.W_o;
    const float* s = W + r * 64 + half * 32;
    #pragma unroll
    for (int i = 0; i < 8; ++i) wg[i] = ((const v4f*)s)[i]; }
  v4f w3[32]; // W_a3 rows {tid, tid+256, tid+512, tid+768} in registers
  float b3[4];
  #pragma unroll
  for (int rr = 0; rr < 4; ++rr) {
    const float* s = p.W_a3 + (size_t)(tid + 256 * rr) * KD;
    #pragma unroll
    for (int i = 0; i < 8; ++i) w3[rr * 8 + i] = ((const v4f*)s)[i];
    b3[rr] = p.b_a3[tid + 256 * rr];
  }
  float kc[32];  // this thread's key column, register-resident
  { const int gcol = sid * 256 + tid;
    #pragma unroll
    for (int k = 0; k < 32; ++k) kc[k] = keys[(size_t)k * N_ENT + gcol]; }
  __syncthreads();

  // produce ri0 for a given tag from LDS ar (8 rows owned by this block)
  auto produce = [&](unsigned tag) {
    const int seg = tid & 31, rl = tid >> 5;
    const float* a = &ar_s[seg * 33];
    float pa = 0.f;
    #pragma unroll
    for (int i = 0; i < 8; ++i) {
      v4f av = *(const v4f*)(a + 4 * i);
      pa += w0[i].x * av.x + w0[i].y * av.y + w0[i].z * av.z + w0[i].w * av.w;
    }
    #pragma unroll
    for (int m = 16; m; m >>= 1) pa += __shfl_xor(pa, m);
    if (seg == 0)
      st_pair(&ri0p[sid * 8 + rl], packf(fmaxf(pa + c0own[rl], 0.f), tag));
  };
  produce(1u);  // ri0 for step 0

  float v_reg = 0.f;
  for (int t = 0; t < steps; ++t) {
    const unsigned tg = (unsigned)(t + 1);

    // ==== Phase A: wait ri0 -> i1 -> LSTM -> LN -> qn -> sweep -> ship ====
    {
      ull u; int guard = 0;
      for (;;) {
        u = ld_pair(&ri0p[tid]);
        if (ptag(u) == tg) break;
        if (++guard > (1 << 20)) break;  // failsafe: never hang
      }
      ri0_s[(tid >> 5) * 33 + (tid & 31)] = pvalf(u);
    }
    bar_lds();
    const int act = (done_s == 0);
    {  // i1 = relu(W_a1 @ ri0 + b_a1)
      const int r = tid >> 3, s8 = tid & 7;
      float p1 = 0.f;
      #pragma unroll
      for (int i = 0; i < 8; ++i) {
        const float* xx = &ri0_s[s8 * 33 + 4 * i];
        p1 += w1[i].x * xx[0] + w1[i].y * xx[1] + w1[i].z * xx[2] + w1[i].w * xx[3];
      }
      #pragma unroll
      for (int m = 4; m; m >>= 1) p1 += __shfl_xor(p1, m);
      if (s8 == 0) x_i1[r] = fmaxf(p1 + b_a1s[r], 0.f);
    }
    bar_lds();
    {  // 4 gate pre-activations
      const int rowg = tid >> 1, g = rowg >> 5, half = tid & 1;
      const float* xsrc = half ? q_s : x_i1;  // x = concat(i1, q)
      float pg = 0.f;
      #pragma unroll
      for (int i = 0; i < 8; ++i)
        pg += wg[i].x * xsrc[4 * i] + wg[i].y * xsrc[4 * i + 1] +
              wg[i].z * xsrc[4 * i + 2] + wg[i].w * xsrc[4 * i + 3];
      pg += __shfl_xor(pg, 1);
      if (!half) {
        pg += gb_s[rowg];
        garr[rowg] = (g == 2) ? tanhf(pg) : 1.f / (1.f + __expf(-pg));
      }
    }
    bar_lds();
    {  // 3 layernorms in parallel (one per wave)
      const int w = tid >> 6, k = tid & 63;
      if (w < 3 && k < 32) {
        float a = (w == 0) ? garr[k] : (w == 1) ? garr[32 + k] * garr[64 + k] : garr[96 + k];
        float s = a;
        #pragma unroll
        for (int m = 16; m; m >>= 1) s += __shfl_xor(s, m);
        const float mean = s * (1.f / 32.f);
        const float d = a - mean;
        float vv = d * d;
        #pragma unroll
        for (int m = 16; m; m >>= 1) vv += __shfl_xor(vv, m);
        vv *= (1.f / 32.f);
        const float y = d * rsqrtf(vv + 1e-5f) * lng_s[k] + lnb_s[k];
        if (w == 0) fog[k] = y; else if (w == 1) rem[k] = y; else og[k] = y;
      }
    }
    bar_lds();
    if (tid < 32) {
      const float nh = rem[tid] + fog[tid] * h_s[tid];
      const float qv = tanhf(nh) * og[tid];
      qnf[tid] = qv;
      if (act) { h_s[tid] = nh; q_s[tid] = qv; }
    }
    bar_lds();
    {  // sweep over this block's 256 register-resident key columns
      float dot = 0.f;
      #pragma unroll
      for (int k = 0; k < 32; ++k) dot += qnf[k] * kc[k];
      const float sig = 1.f / (1.f + __expf(-dot));
      const float v = __expf(__logf(sig) / 0.8f);  // sig^(1/TEMP)
      v_reg = v;
      float sv = v, mv = v;
      int mi = (sid << 8) + tid;
      #pragma unroll
      for (int m = 32; m; m >>= 1) {
        sv += __shfl_xor(sv, m);
        const float ov = __shfl_xor(mv, m);
        const int oi = __shfl_xor(mi, m);
        if (ov > mv || (ov == mv && oi < mi)) { mv = ov; mi = oi; }
      }
      const int wv = tid >> 6;
      if ((tid & 63) == 0) { reds[wv] = sv; rmaxs[wv] = mv; ridxs[wv] = mi; }
    }
    bar_lds();
    {  // ALL threads: block-local reduce; scalar record + column ship together
      const float Sb = ((reds[0] + reds[1]) + reds[2]) + reds[3];
      float Mb = rmaxs[0]; int Ib = ridxs[0];
      #pragma unroll
      for (int i2 = 1; i2 < 4; ++i2)
        if (rmaxs[i2] > Mb || (rmaxs[i2] == Mb && ridxs[i2] < Ib)) { Mb = rmaxs[i2]; Ib = ridxs[i2]; }
      ull* rec = &partp[sid * 40];
      if (tid == 0) {
        st_pair(&rec[0], packf(Sb, tg));
        st_pair(&rec[1], packf(Mb, tg));
        st_pair(&rec[2], packi(Ib, tg));
      }
      if (((sid << 8) | tid) == Ib) {
        #pragma unroll
        for (int k = 0; k < 32; ++k) st_pair(&rec[3 + k], packf(kc[k], tg));
      }
    }

    // ==== Phase B: wait partials -> redundant reduce/pick/ar -> ri0(t+1) ====
    {
      const int b = tid >> 3, i = tid & 7;
      ull* rec = &partp[b * 40];
      ull u0, u1, u2, u3, u4 = 0;
      const bool f5 = (i < 3);
      int guard = 0;
      for (;;) {
        u0 = ld_pair(&rec[i]);
        u1 = ld_pair(&rec[i + 8]);
        u2 = ld_pair(&rec[i + 16]);
        u3 = ld_pair(&rec[i + 24]);
        if (f5) u4 = ld_pair(&rec[i + 32]);
        bool ok = (ptag(u0) == tg) & (ptag(u1) == tg) & (ptag(u2) == tg) &
                  (ptag(u3) == tg) & (!f5 || (ptag(u4) == tg));
        if (ok) break;
        if (++guard > (1 << 20)) break;
      }
      ull us[5] = {u0, u1, u2, u3, u4};
      #pragma unroll
      for (int s5 = 0; s5 < 5; ++s5) {
        const int j = i + 8 * s5;
        if (j > 34) break;
        if (j == 0) psums[b] = pvalf(us[s5]);
        else if (j == 1) pmaxs[b] = pvalf(us[s5]);
        else if (j == 2) pidxs[b] = (int)(unsigned)us[s5];
        else cand_s[b * 32 + (j - 3)] = pvalf(us[s5]);
      }
    }
    bar_lds();
    // every thread redundantly: vectorized loads -> register reduce
    float psv[32], pmv[32]; int piv[32];
    #pragma unroll
    for (int g = 0; g < 8; ++g) {
      v4f xs = *(const v4f*)&psums[4 * g];
      v4f xm = *(const v4f*)&pmaxs[4 * g];
      psv[4*g] = xs.x; psv[4*g+1] = xs.y; psv[4*g+2] = xs.z; psv[4*g+3] = xs.w;
      pmv[4*g] = xm.x; pmv[4*g+1] = xm.y; pmv[4*g+2] = xm.z; pmv[4*g+3] = xm.w;
      const int* pp = &pidxs[4 * g];
      piv[4*g] = pp[0]; piv[4*g+1] = pp[1]; piv[4*g+2] = pp[2]; piv[4*g+3] = pp[3];
    }
    float S = psv[0], M = pmv[0]; int I = piv[0];
    #pragma unroll
    for (int j = 1; j < 32; ++j) {
      S += psv[j];
      if (pmv[j] > M || (pmv[j] == M && piv[j] < I)) { M = pmv[j]; I = piv[j]; }
    }
    const int cb = I >> 8;
    float cc[32], sm = 0.f;
    #pragma unroll
    for (int g = 0; g < 8; ++g) {
      v4f x = *(const v4f*)&cand_s[cb * 32 + 4 * g];
      cc[4*g] = x.x; cc[4*g+1] = x.y; cc[4*g+2] = x.z; cc[4*g+3] = x.w;
      sm += (x.x + x.y) + (x.z + x.w);
    }
    const float mean = sm * (1.f / 32.f);
    int nanf = 0;
    float dl0 = b3[0], dl1 = b3[1], dl2 = b3[2], dl3 = b3[3];
    #pragma unroll
    for (int c = 0; c < 32; ++c) {
      const float cv = cc[c] - mean;
      nanf |= (cv != cv) ? 1 : 0;
      dl0 += w3[c >> 2][c & 3] * cv;
      dl1 += w3[8 + (c >> 2)][c & 3] * cv;
      dl2 += w3[16 + (c >> 2)][c & 3] * cv;
      dl3 += w3[24 + (c >> 2)][c & 3] * cv;
    }
    const unsigned mw = maskb[I >> 5];
    const int valid = (S != 0.f) ? 1 : 0;
    const int hit = (act && valid && ((mw >> (I & 31)) & 1)) ? 1 : 0;
    const int nf = nanf ? 0 : 1;
    if (hit && nf) {  // replicated ar update, 4 rows per thread, weights in regs
      if (dl0 > 0.f) ar_s[(tid >> 5) * 33 + (tid & 31)] += dl0;
      const int r1 = tid + 256, r2 = tid + 512, r3 = tid + 768;
      if (dl1 > 0.f) ar_s[(r1 >> 5) * 33 + (r1 & 31)] += dl1;
      if (dl2 > 0.f) ar_s[(r2 >> 5) * 33 + (r2 & 31)] += dl2;
      if (dl3 > 0.f) ar_s[(r3 >> 5) * 33 + (r3 & 31)] += dl3;
    }
    bar_lds();
    produce(tg + 1u);  // ri0 for step t+1 (most urgent store first)
    if (tid == 0 && hit) {  // ordered before next reads by Phase A's first bar
      maskb[I >> 5] = mw & ~(1u << (I & 31));
      selb[I >> 5] |= (1u << (I & 31));
      if (!nf) done_s = 1;
    }
    {  // row write for step t (never drained inside the loop)
      const float rowv = (act && valid) ? (v_reg / S) : 0.f;
      __builtin_nontemporal_store(rowv, p.out + (size_t)t * N_ENT + (sid << 8) + tid);
    }
  }
  __syncthreads();

  // ==== epilogue: sel_out and ar_out (replicated state) ====
  if (sid == 0) {
    for (int i = tid; i < N_ENT; i += 256)
      p.out[NN + i] = ((selb[i >> 5] >> (i & 31)) & 1u) ? 1.f : 0.f;
  } else if (sid == 1) {
    for (int i = tid; i < ARD; i += 256)
      p.out[NN + N_ENT + i] = ar_s[(i >> 5) * 33 + (i & 31)];
  }
}

extern "C" void kernel_launch(void* const* d_in, const int* in_sizes, int n_in,
                              void* d_out, int out_size, void* d_ws, size_t ws_size,
                              hipStream_t stream) {
  (void)in_sizes; (void)n_in; (void)out_size; (void)ws_size;
  Params p;
  p.um    = (const float*)d_in[0];
  p.emask = (const float*)d_in[1];
  p.enc   = (const float*)d_in[2];
  p.arin  = (const float*)d_in[3];
  p.W_fe  = (const float*)d_in[4];
  p.b_fe  = (const float*)d_in[5];
  p.W_k   = (const float*)d_in[6];
  p.b_k   = (const float*)d_in[7];
  p.W_a0  = (const float*)d_in[8];
  p.b_a0  = (const float*)d_in[9];
  p.W_a1  = (const float*)d_in[10];
  p.b_a1  = (const float*)d_in[11];
  p.W_f   = (const float*)d_in[12];
  p.b_f   = (const float*)d_in[13];
  p.W_i0  = (const float*)d_in[14];
  p.b_i0  = (const float*)d_in[15];
  p.W_i1  = (const float*)d_in[16];
  p.b_i1  = (const float*)d_in[17];
  p.W_o   = (const float*)d_in[18];
  p.b_o   = (const float*)d_in[19];
  p.ln_g  = (const float*)d_in[20];
  p.ln_b  = (const float*)d_in[21];
  p.W_a3  = (const float*)d_in[22];
  p.b_a3  = (const float*)d_in[23];
  p.ct    = (const int*)d_in[24];
  p.out   = (float*)d_out;
  p.wsf   = (float*)d_ws;
  p.wsi   = (int*)d_ws;

  hipLaunchKernelGGL(k_init, dim3(NBLK), dim3(256), 0, stream, p);
  hipLaunchKernelGGL(k_scan, dim3(NBLK), dim3(256), 0, stream, p);
}

// Round 5
// 1038.295 us; speedup vs baseline: 1.2535x; 1.2535x over previous
//
#include <hip/hip_runtime.h>
#include <math.h>

// BWNet scan v5 (resubmit; prior bench failed on infra, no counters returned).
//  - k_init (256 blocks): keys GEMM + func_embed + tag-pair zero + ZEROES the
//    whole 268MB unit_logits output at full HBM BW (~50us).
//  - k_scan (32 blocks ONLY): the 64-step scan runs on an otherwise-idle GPU;
//    its row stores overwrite the zeroed rows. No concurrent store stream ->
//    polls and ships see idle-latency LLC.
//  - Tagged-word exchange (v2-proven): 2 exchanges/step, s_sleep polls.
//  - In-loop barriers are lgkmcnt-only (never drain global stores in-loop).
//  - Single-barrier ship: all threads compute block argmax; record + column
//    stores issue together.

typedef float v4f __attribute__((ext_vector_type(4)));
typedef unsigned long long ull;

#define N_ENT 8192
#define EMB   256
#define KD    32
#define ARD   1024
#define UT    233
#define NSCAN 32

// workspace float-index offsets
#define WS_KEYS 0         // 32*8192 floats, k-major: keys[k*8192+j]
#define WS_C0   262144    // 256: b_a0 + relu(W_fe@um + b_fe)
#define WS_PAIR 262400    // tagged-pair region (byte 1049600, 8B aligned)
#define PR_RI0  0         // 256 pairs: ri0[j], written by scan block j>>3
#define PR_PART 256       // 32 blocks * 40 pairs: [0]=psum [1]=pmax [2]=pidx [3..34]=cand
#define NPAIRS  (256 + 32 * 40)

struct Params {
  const float *um, *emask, *enc, *arin, *W_fe, *b_fe, *W_k, *b_k,
              *W_a0, *b_a0, *W_a1, *b_a1, *W_f, *b_f, *W_i0, *b_i0,
              *W_i1, *b_i1, *W_o, *b_o, *ln_g, *ln_b, *W_a3, *b_a3;
  const int* ct;
  float* out;
  float* wsf;
  int*   wsi;
};

__device__ __forceinline__ ull ld_pair(ull* p_) {
  return __hip_atomic_load(p_, __ATOMIC_RELAXED, __HIP_MEMORY_SCOPE_AGENT);
}
__device__ __forceinline__ void st_pair(ull* p_, ull v) {
  __hip_atomic_store(p_, v, __ATOMIC_RELAXED, __HIP_MEMORY_SCOPE_AGENT);
}
__device__ __forceinline__ ull packf(float v, unsigned tag) {
  return ((ull)tag << 32) | (ull)__float_as_uint(v);
}
__device__ __forceinline__ ull packi(int v, unsigned tag) {
  return ((ull)tag << 32) | (ull)(unsigned)v;
}
__device__ __forceinline__ unsigned ptag(ull u) { return (unsigned)(u >> 32); }
__device__ __forceinline__ float pvalf(ull u) { return __uint_as_float((unsigned)u); }

// LDS-only barrier: drains lgkmcnt but NOT vmcnt (global stores keep flying).
__device__ __forceinline__ void bar_lds() {
  asm volatile("s_waitcnt lgkmcnt(0)\n\ts_barrier" ::: "memory");
}

// ---------------- init: keys GEMM, func_embed, pair zero, OUTPUT ZERO ----------------
__global__ __launch_bounds__(256) void k_init(Params p) {
  __shared__ float enc_s[32 * 260];
  __shared__ float um_s[UT];
  const int tid = threadIdx.x, bid = blockIdx.x;
  float* keys = p.wsf + WS_KEYS;
  const size_t NN = (size_t)N_ENT * N_ENT;

  if (bid == 0 && tid < UT) um_s[tid] = p.um[tid];
  if (bid == 3) {  // zero all tag pairs (tag 0 matches no step tag 1..66)
    ull* pr = (ull*)(p.wsf + WS_PAIR);
    for (int i = tid; i < NPAIRS; i += 256) pr[i] = 0ull;
  }

  const int j0 = bid * 32;
  #pragma unroll
  for (int i = 0; i < 8; ++i) {
    int idx = i * 256 + tid;
    int row = idx >> 6, c4 = idx & 63;
    v4f v = *(const v4f*)(p.enc + (size_t)(j0 + row) * EMB + c4 * 4);
    *(v4f*)&enc_s[row * 260 + c4 * 4] = v;
  }
  __syncthreads();
  {
    const int jl = tid >> 3, kg = tid & 7;
    float acc[4];
    #pragma unroll
    for (int kk = 0; kk < 4; ++kk) acc[kk] = p.b_k[kg * 4 + kk];
    for (int e4 = 0; e4 < 64; ++e4) {
      v4f x = *(const v4f*)&enc_s[jl * 260 + e4 * 4];
      #pragma unroll
      for (int kk = 0; kk < 4; ++kk) {
        v4f w = *(const v4f*)(p.W_k + (size_t)(kg * 4 + kk) * EMB + e4 * 4);
        acc[kk] += x.x * w.x + x.y * w.y + x.z * w.z + x.w * w.w;
      }
    }
    const int j = j0 + jl;
    #pragma unroll
    for (int kk = 0; kk < 4; ++kk) keys[(size_t)(kg * 4 + kk) * N_ENT + j] = acc[kk];
  }
  if (bid == 0) {
    float a = p.b_fe[tid];
    const float* wr = p.W_fe + (size_t)tid * UT;
    for (int u = 0; u < UT; ++u) a += wr[u] * um_s[u];
    p.wsf[WS_C0 + tid] = fmaxf(a, 0.f) + p.b_a0[tid];
  }

  // zero the whole unit_logits region at full 256-block HBM bandwidth
  {
    v4f z = (v4f){0.f, 0.f, 0.f, 0.f};
    v4f* o4 = (v4f*)p.out;
    const size_t tot = NN / 4;
    for (size_t i = (size_t)bid * 256 + tid; i < tot; i += (size_t)256 * 256)
      __builtin_nontemporal_store(z, o4 + i);
  }
}

// ---------------- main: 32-block scan on an idle GPU ----------------
__global__ __launch_bounds__(256, 1) void k_scan(Params p) {
  const int tid = threadIdx.x, bid = blockIdx.x;
  int ctv = p.ct[0];
  const int steps = ctv < 0 ? 0 : (ctv > 64 ? 64 : ctv);
  const size_t NN = (size_t)N_ENT * N_ENT;

  __shared__ float ar_s[32 * 33];
  __shared__ float cand_s[32 * 32];
  __shared__ float ri0_s[8 * 33];
  __shared__ unsigned maskb[256], selb[256];
  __shared__ float x_i1[32], q_s[32], h_s[32], qnf[32];
  __shared__ float garr[128], fog[32], rem[32], og[32], cent[32];
  __shared__ float b_a1s[32], gb_s[128], lng_s[32], lnb_s[32], c0own[8];
  __shared__ float psums[32], pmaxs[32];
  __shared__ int   pidxs[32];
  __shared__ float reds[4], rmaxs[4];
  __shared__ int   ridxs[4];
  __shared__ float ssum_s;
  __shared__ int   upd_s, done_s;

  ull* ri0p  = (ull*)(p.wsf + WS_PAIR) + PR_RI0;
  ull* partp = (ull*)(p.wsf + WS_PAIR) + PR_PART;
  const float* keys = p.wsf + WS_KEYS;

  // ---- preamble ----
  for (int i = tid; i < ARD; i += 256) ar_s[(i >> 5) * 33 + (i & 31)] = p.arin[i];
  {
    unsigned mb = 0u;
    const float* em = p.emask + (size_t)tid * 32;
    #pragma unroll
    for (int j = 0; j < 32; ++j) mb |= (em[j] != 0.f) ? (1u << j) : 0u;
    maskb[tid] = mb; selb[tid] = 0u;
  }
  if (tid < 32) {
    b_a1s[tid] = p.b_a1[tid];
    lng_s[tid] = p.ln_g[tid]; lnb_s[tid] = p.ln_b[tid];
    q_s[tid] = 0.f; h_s[tid] = 0.f; qnf[tid] = 0.f; x_i1[tid] = 0.f;
  }
  if (tid < 128) {
    const int g = tid >> 5, r = tid & 31;
    const float* bg = (g == 0) ? p.b_f : (g == 1) ? p.b_i0 : (g == 2) ? p.b_i1 : p.b_o;
    gb_s[tid] = bg[r];
  }
  if (tid < 8) c0own[tid] = p.wsf[WS_C0 + bid * 8 + tid];
  if (tid == 0) done_s = 0;

  v4f w0[8];
  { const float* s = p.W_a0 + (size_t)(bid * 8 + (tid >> 5)) * ARD + (tid & 31) * 32;
    #pragma unroll
    for (int i = 0; i < 8; ++i) w0[i] = ((const v4f*)s)[i]; }
  v4f w1[8];
  { const float* s = p.W_a1 + (size_t)(tid >> 3) * EMB + (tid & 7) * 32;
    #pragma unroll
    for (int i = 0; i < 8; ++i) w1[i] = ((const v4f*)s)[i]; }
  v4f wg[8];
  { const int rowg = tid >> 1, g = rowg >> 5, r = rowg & 31, half = tid & 1;
    const float* W = (g == 0) ? p.W_f : (g == 1) ? p.W_i0 : (g == 2) ? p.W_i1 : p.W_o;
    const float* s = W + r * 64 + half * 32;
    #pragma unroll
    for (int i = 0; i < 8; ++i) wg[i] = ((const v4f*)s)[i]; }
  float kc[32];
  { const int gcol = bid * 256 + tid;
    #pragma unroll
    for (int k = 0; k < 32; ++k) kc[k] = keys[(size_t)k * N_ENT + gcol]; }
  __syncthreads();

  auto produce = [&](unsigned tag) {
    const int seg = tid & 31, rl = tid >> 5;
    const float* a = &ar_s[seg * 33];
    float pa = 0.f;
    #pragma unroll
    for (int i = 0; i < 8; ++i) {
      v4f av = *(const v4f*)(a + 4 * i);
      pa += w0[i].x * av.x + w0[i].y * av.y + w0[i].z * av.z + w0[i].w * av.w;
    }
    #pragma unroll
    for (int m = 16; m; m >>= 1) pa += __shfl_xor(pa, m);
    if (seg == 0)
      st_pair(&ri0p[bid * 8 + rl], packf(fmaxf(pa + c0own[rl], 0.f), tag));
  };
  produce(1u);  // ri0 for step 0

  float v_reg = 0.f;
  for (int t = 0; t < steps; ++t) {
    const unsigned tg = (unsigned)(t + 1);

    // ==== Phase A: wait ri0 -> i1 -> LSTM -> LN -> qn -> sweep -> ship ====
    {
      ull u; int guard = 0;
      for (;;) {
        u = ld_pair(&ri0p[tid]);
        if (ptag(u) == tg) break;
        if (++guard > (1 << 20)) break;  // failsafe: never hang
        __builtin_amdgcn_s_sleep(1);
      }
      ri0_s[(tid >> 5) * 33 + (tid & 31)] = pvalf(u);
    }
    bar_lds();
    const int act = (done_s == 0);
    {  // i1 = relu(W_a1 @ ri0 + b_a1)
      const int r = tid >> 3, s8 = tid & 7;
      float p1 = 0.f;
      #pragma unroll
      for (int i = 0; i < 8; ++i) {
        const float* xx = &ri0_s[s8 * 33 + 4 * i];
        p1 += w1[i].x * xx[0] + w1[i].y * xx[1] + w1[i].z * xx[2] + w1[i].w * xx[3];
      }
      #pragma unroll
      for (int m = 4; m; m >>= 1) p1 += __shfl_xor(p1, m);
      if (s8 == 0) x_i1[r] = fmaxf(p1 + b_a1s[r], 0.f);
    }
    bar_lds();
    {  // 4 gate pre-activations
      const int rowg = tid >> 1, g = rowg >> 5, half = tid & 1;
      const float* xsrc = half ? q_s : x_i1;  // x = concat(i1, q)
      float pg = 0.f;
      #pragma unroll
      for (int i = 0; i < 8; ++i)
        pg += wg[i].x * xsrc[4 * i] + wg[i].y * xsrc[4 * i + 1] +
              wg[i].z * xsrc[4 * i + 2] + wg[i].w * xsrc[4 * i + 3];
      pg += __shfl_xor(pg, 1);
      if (!half) {
        pg += gb_s[rowg];
        garr[rowg] = (g == 2) ? tanhf(pg) : 1.f / (1.f + __expf(-pg));
      }
    }
    bar_lds();
    {  // 3 layernorms in parallel (one per wave)
      const int w = tid >> 6, k = tid & 63;
      if (w < 3 && k < 32) {
        float a = (w == 0) ? garr[k] : (w == 1) ? garr[32 + k] * garr[64 + k] : garr[96 + k];
        float s = a;
        #pragma unroll
        for (int m = 16; m; m >>= 1) s += __shfl_xor(s, m);
        const float mean = s * (1.f / 32.f);
        const float d = a - mean;
        float vv = d * d;
        #pragma unroll
        for (int m = 16; m; m >>= 1) vv += __shfl_xor(vv, m);
        vv *= (1.f / 32.f);
        const float y = d * rsqrtf(vv + 1e-5f) * lng_s[k] + lnb_s[k];
        if (w == 0) fog[k] = y; else if (w == 1) rem[k] = y; else og[k] = y;
      }
    }
    bar_lds();
    if (tid < 32) {
      const float nh = rem[tid] + fog[tid] * h_s[tid];
      const float qv = tanhf(nh) * og[tid];
      qnf[tid] = qv;
      if (act) { h_s[tid] = nh; q_s[tid] = qv; }
    }
    bar_lds();
    {  // sweep over this block's 256 register-resident key columns
      float dot = 0.f;
      #pragma unroll
      for (int k = 0; k < 32; ++k) dot += qnf[k] * kc[k];
      const float sig = 1.f / (1.f + __expf(-dot));
      const float v = __expf(__logf(sig) / 0.8f);  // sig^(1/TEMP)
      v_reg = v;
      float sv = v, mv = v;
      int mi = (bid << 8) + tid;
      #pragma unroll
      for (int m = 32; m; m >>= 1) {
        sv += __shfl_xor(sv, m);
        const float ov = __shfl_xor(mv, m);
        const int oi = __shfl_xor(mi, m);
        if (ov > mv || (ov == mv && oi < mi)) { mv = ov; mi = oi; }
      }
      const int wv = tid >> 6;
      if ((tid & 63) == 0) { reds[wv] = sv; rmaxs[wv] = mv; ridxs[wv] = mi; }
    }
    bar_lds();
    {  // ALL threads: block reduce; record + column ship issue together
      const float Sb = ((reds[0] + reds[1]) + reds[2]) + reds[3];
      float Mb = rmaxs[0]; int Ib = ridxs[0];
      #pragma unroll
      for (int i2 = 1; i2 < 4; ++i2)
        if (rmaxs[i2] > Mb || (rmaxs[i2] == Mb && ridxs[i2] < Ib)) { Mb = rmaxs[i2]; Ib = ridxs[i2]; }
      ull* rec = &partp[bid * 40];
      if (tid == 0) {
        st_pair(&rec[0], packf(Sb, tg));
        st_pair(&rec[1], packf(Mb, tg));
        st_pair(&rec[2], packi(Ib, tg));
      }
      if (((bid << 8) | tid) == Ib) {
        #pragma unroll
        for (int k = 0; k < 32; ++k) st_pair(&rec[3 + k], packf(kc[k], tg));
      }
    }

    // ==== Phase B: wait partials -> tid<32 reduce/pick -> ar -> ri0(t+1) ====
    {
      const int b = tid >> 3, i = tid & 7;
      ull* rec = &partp[b * 40];
      ull u0, u1, u2, u3, u4 = 0;
      const bool f5 = (i < 3);
      int guard = 0;
      for (;;) {
        u0 = ld_pair(&rec[i]);
        u1 = ld_pair(&rec[i + 8]);
        u2 = ld_pair(&rec[i + 16]);
        u3 = ld_pair(&rec[i + 24]);
        if (f5) u4 = ld_pair(&rec[i + 32]);
        bool ok = (ptag(u0) == tg) & (ptag(u1) == tg) & (ptag(u2) == tg) &
                  (ptag(u3) == tg) & (!f5 || (ptag(u4) == tg));
        if (ok) break;
        if (++guard > (1 << 20)) break;
        __builtin_amdgcn_s_sleep(1);
      }
      ull us[5] = {u0, u1, u2, u3, u4};
      #pragma unroll
      for (int s5 = 0; s5 < 5; ++s5) {
        const int j = i + 8 * s5;
        if (j > 34) break;
        if (j == 0) psums[b] = pvalf(us[s5]);
        else if (j == 1) pmaxs[b] = pvalf(us[s5]);
        else if (j == 2) pidxs[b] = (int)(unsigned)us[s5];
        else cand_s[b * 32 + (j - 3)] = pvalf(us[s5]);
      }
    }
    bar_lds();
    if (tid < 32) {  // global reduce + centered selection (v2-proven shape)
      float s = psums[tid], m = pmaxs[tid];
      int ii = pidxs[tid];
      #pragma unroll
      for (int mm = 16; mm; mm >>= 1) {
        s += __shfl_xor(s, mm);
        const float om = __shfl_xor(m, mm);
        const int oi = __shfl_xor(ii, mm);
        if (om > m || (om == m && oi < ii)) { m = om; ii = oi; }
      }
      const float kv = cand_s[(ii >> 8) * 32 + tid];  // keys[:, pick]
      float mn = kv;
      #pragma unroll
      for (int mm = 16; mm; mm >>= 1) mn += __shfl_xor(mn, mm);
      mn *= (1.f / 32.f);
      const float cv = kv - mn;
      cent[tid] = cv;
      const unsigned long long bb = __ballot(cv != cv);
      if (tid == 0) {
        const int valid = (s != 0.f);
        const int nf = (bb == 0) ? 1 : 0;
        const unsigned mw = maskb[ii >> 5];
        const int hit = (act && valid && ((mw >> (ii & 31)) & 1)) ? 1 : 0;
        ssum_s = s;
        upd_s = (hit && nf) ? 1 : 0;
        if (hit) {
          maskb[ii >> 5] = mw & ~(1u << (ii & 31));
          selb[ii >> 5] |= (1u << (ii & 31));
          if (!nf) done_s = 1;
        }
      }
    }
    bar_lds();
    {  // row write for step t (never drained inside the loop)
      const float S = ssum_s;
      const float rowv = (act && (S != 0.f)) ? (v_reg / S) : 0.f;
      __builtin_nontemporal_store(rowv, p.out + (size_t)t * N_ENT + (bid << 8) + tid);
    }
    if (upd_s) {  // replicated ar update: 4 rows/thread, W_a3 from L2
      #pragma unroll
      for (int rr = 0; rr < 4; ++rr) {
        const int r = tid + rr * 256;
        const float* wr = p.W_a3 + (size_t)r * KD;
        float dl = p.b_a3[r];
        #pragma unroll
        for (int c4 = 0; c4 < 8; ++c4) {
          v4f wv4 = *(const v4f*)(wr + 4 * c4);
          dl += wv4.x * cent[4 * c4] + wv4.y * cent[4 * c4 + 1] +
                wv4.z * cent[4 * c4 + 2] + wv4.w * cent[4 * c4 + 3];
        }
        if (dl > 0.f) ar_s[(r >> 5) * 33 + (r & 31)] += dl;
      }
    }
    bar_lds();
    produce(tg + 1u);  // ri0 for step t+1
  }
  __syncthreads();

  // ==== epilogue: sel_out and ar_out (replicated state) ====
  if (bid == 0) {
    for (int i = tid; i < N_ENT; i += 256)
      p.out[NN + i] = ((selb[i >> 5] >> (i & 31)) & 1u) ? 1.f : 0.f;
  } else if (bid == 1) {
    for (int i = tid; i < ARD; i += 256)
      p.out[NN + N_ENT + i] = ar_s[(i >> 5) * 33 + (i & 31)];
  }
}

extern "C" void kernel_launch(void* const* d_in, const int* in_sizes, int n_in,
                              void* d_out, int out_size, void* d_ws, size_t ws_size,
                              hipStream_t stream) {
  (void)in_sizes; (void)n_in; (void)out_size; (void)ws_size;
  Params p;
  p.um    = (const float*)d_in[0];
  p.emask = (const float*)d_in[1];
  p.enc   = (const float*)d_in[2];
  p.arin  = (const float*)d_in[3];
  p.W_fe  = (const float*)d_in[4];
  p.b_fe  = (const float*)d_in[5];
  p.W_k   = (const float*)d_in[6];
  p.b_k   = (const float*)d_in[7];
  p.W_a0  = (const float*)d_in[8];
  p.b_a0  = (const float*)d_in[9];
  p.W_a1  = (const float*)d_in[10];
  p.b_a1  = (const float*)d_in[11];
  p.W_f   = (const float*)d_in[12];
  p.b_f   = (const float*)d_in[13];
  p.W_i0  = (const float*)d_in[14];
  p.b_i0  = (const float*)d_in[15];
  p.W_i1  = (const float*)d_in[16];
  p.b_i1  = (const float*)d_in[17];
  p.W_o   = (const float*)d_in[18];
  p.b_o   = (const float*)d_in[19];
  p.ln_g  = (const float*)d_in[20];
  p.ln_b  = (const float*)d_in[21];
  p.W_a3  = (const float*)d_in[22];
  p.b_a3  = (const float*)d_in[23];
  p.ct    = (const int*)d_in[24];
  p.out   = (float*)d_out;
  p.wsf   = (float*)d_ws;
  p.wsi   = (int*)d_ws;

  hipLaunchKernelGGL(k_init, dim3(256), dim3(256), 0, stream, p);
  hipLaunchKernelGGL(k_scan, dim3(NSCAN), dim3(256), 0, stream, p);
}

// Round 6
// 1019.010 us; speedup vs baseline: 1.2773x; 1.0189x over previous
//
#include <hip/hip_runtime.h>
#include <math.h>

// BWNet scan v6: poll-narrowed, barrier-slim persistent scan.
//  - k_init (256 blocks): keys GEMM + func_embed + tag zero + output zero.
//  - k_scan (32 blocks): tagged-word exchange, 2 edges/step, but ONLY WAVE 0
//    polls (others park at s_barrier -> no MALL poll traffic), and the whole
//    LSTM chain runs solo on wave 0 via shfl (5 in-loop barriers, was 9).
//  - W_a1 + gate weights in LDS; W_a3 in VGPRs; keys in VGPRs.

typedef float v4f __attribute__((ext_vector_type(4)));
typedef unsigned long long ull;

#define N_ENT 8192
#define EMB   256
#define KD    32
#define ARD   1024
#define UT    233
#define NSCAN 32

// workspace float-index offsets
#define WS_KEYS 0         // 32*8192 floats, k-major: keys[k*8192+j]
#define WS_C0   262144    // 256: b_a0 + relu(W_fe@um + b_fe)
#define WS_PAIR 262400    // tagged-pair region (byte 1049600, 8B aligned)
#define PR_RI0  0         // 256 pairs: ri0[j], written by scan block j>>3
#define PR_PART 256       // 32 blocks * 40 pairs: [0]=psum [1]=pmax [2]=pidx [3..34]=cand
#define NPAIRS  (256 + 32 * 40)

struct Params {
  const float *um, *emask, *enc, *arin, *W_fe, *b_fe, *W_k, *b_k,
              *W_a0, *b_a0, *W_a1, *b_a1, *W_f, *b_f, *W_i0, *b_i0,
              *W_i1, *b_i1, *W_o, *b_o, *ln_g, *ln_b, *W_a3, *b_a3;
  const int* ct;
  float* out;
  float* wsf;
  int*   wsi;
};

__device__ __forceinline__ ull ld_pair(ull* p_) {
  return __hip_atomic_load(p_, __ATOMIC_RELAXED, __HIP_MEMORY_SCOPE_AGENT);
}
__device__ __forceinline__ void st_pair(ull* p_, ull v) {
  __hip_atomic_store(p_, v, __ATOMIC_RELAXED, __HIP_MEMORY_SCOPE_AGENT);
}
__device__ __forceinline__ ull packf(float v, unsigned tag) {
  return ((ull)tag << 32) | (ull)__float_as_uint(v);
}
__device__ __forceinline__ ull packi(int v, unsigned tag) {
  return ((ull)tag << 32) | (ull)(unsigned)v;
}
__device__ __forceinline__ unsigned ptag(ull u) { return (unsigned)(u >> 32); }
__device__ __forceinline__ float pvalf(ull u) { return __uint_as_float((unsigned)u); }

// LDS-only barrier: drains lgkmcnt but NOT vmcnt (global stores keep flying).
__device__ __forceinline__ void bar_lds() {
  asm volatile("s_waitcnt lgkmcnt(0)\n\ts_barrier" ::: "memory");
}

// ---------------- init: keys GEMM, func_embed, pair zero, OUTPUT ZERO ----------------
__global__ __launch_bounds__(256) void k_init(Params p) {
  __shared__ float enc_s[32 * 260];
  __shared__ float um_s[UT];
  const int tid = threadIdx.x, bid = blockIdx.x;
  float* keys = p.wsf + WS_KEYS;
  const size_t NN = (size_t)N_ENT * N_ENT;

  if (bid == 0 && tid < UT) um_s[tid] = p.um[tid];
  if (bid == 3) {  // zero all tag pairs (tag 0 matches no step tag 1..66)
    ull* pr = (ull*)(p.wsf + WS_PAIR);
    for (int i = tid; i < NPAIRS; i += 256) pr[i] = 0ull;
  }

  const int j0 = bid * 32;
  #pragma unroll
  for (int i = 0; i < 8; ++i) {
    int idx = i * 256 + tid;
    int row = idx >> 6, c4 = idx & 63;
    v4f v = *(const v4f*)(p.enc + (size_t)(j0 + row) * EMB + c4 * 4);
    *(v4f*)&enc_s[row * 260 + c4 * 4] = v;
  }
  __syncthreads();
  {
    const int jl = tid >> 3, kg = tid & 7;
    float acc[4];
    #pragma unroll
    for (int kk = 0; kk < 4; ++kk) acc[kk] = p.b_k[kg * 4 + kk];
    for (int e4 = 0; e4 < 64; ++e4) {
      v4f x = *(const v4f*)&enc_s[jl * 260 + e4 * 4];
      #pragma unroll
      for (int kk = 0; kk < 4; ++kk) {
        v4f w = *(const v4f*)(p.W_k + (size_t)(kg * 4 + kk) * EMB + e4 * 4);
        acc[kk] += x.x * w.x + x.y * w.y + x.z * w.z + x.w * w.w;
      }
    }
    const int j = j0 + jl;
    #pragma unroll
    for (int kk = 0; kk < 4; ++kk) keys[(size_t)(kg * 4 + kk) * N_ENT + j] = acc[kk];
  }
  if (bid == 0) {
    float a = p.b_fe[tid];
    const float* wr = p.W_fe + (size_t)tid * UT;
    for (int u = 0; u < UT; ++u) a += wr[u] * um_s[u];
    p.wsf[WS_C0 + tid] = fmaxf(a, 0.f) + p.b_a0[tid];
  }

  // zero the whole unit_logits region at full 256-block HBM bandwidth
  {
    v4f z = (v4f){0.f, 0.f, 0.f, 0.f};
    v4f* o4 = (v4f*)p.out;
    const size_t tot = NN / 4;
    for (size_t i = (size_t)bid * 256 + tid; i < tot; i += (size_t)256 * 256)
      __builtin_nontemporal_store(z, o4 + i);
  }
}

// ---------------- main: 32-block scan, wave0-narrow polling ----------------
__global__ __launch_bounds__(256, 1) void k_scan(Params p) {
  const int tid = threadIdx.x, bid = blockIdx.x;
  int ctv = p.ct[0];
  const int steps = ctv < 0 ? 0 : (ctv > 64 ? 64 : ctv);
  const size_t NN = (size_t)N_ENT * N_ENT;

  __shared__ float w1_lds[32 * 257];   // W_a1 32x256, stride 257 (bank-safe)
  __shared__ float wg_lds[128 * 65];   // gates 128x64, stride 65 (bank-safe)
  __shared__ float ar_s[32 * 33];
  __shared__ float ri0f[256];
  __shared__ float xcat[64];           // [0..32)=i1, [32..64)=q
  __shared__ float h_s[32], qnf[32], cent[32];
  __shared__ unsigned maskb[256], selb[256];
  __shared__ float b_a1s[32], gb_s[128], lng_s[32], lnb_s[32], c0own[8];
  __shared__ float reds[4], rmaxs[4];
  __shared__ int   ridxs[4];
  __shared__ float ssum_s;
  __shared__ int   upd_s, done_s;

  ull* ri0p  = (ull*)(p.wsf + WS_PAIR) + PR_RI0;
  ull* partp = (ull*)(p.wsf + WS_PAIR) + PR_PART;
  const float* keys = p.wsf + WS_KEYS;

  // ---- preamble: replicated state + weights into LDS / registers ----
  for (int i = tid; i < ARD; i += 256) ar_s[(i >> 5) * 33 + (i & 31)] = p.arin[i];
  {
    unsigned mb = 0u;
    const float* em = p.emask + (size_t)tid * 32;
    #pragma unroll
    for (int j = 0; j < 32; ++j) mb |= (em[j] != 0.f) ? (1u << j) : 0u;
    maskb[tid] = mb; selb[tid] = 0u;
  }
  for (int idx = tid; idx < 32 * 256; idx += 256) {  // W_a1 -> LDS
    const int r = idx >> 8, c = idx & 255;
    w1_lds[r * 257 + c] = p.W_a1[idx];
  }
  for (int idx = tid; idx < 128 * 64; idx += 256) {  // gate weights -> LDS
    const int row = idx >> 6, c = idx & 63;
    const float* W = (row < 32) ? p.W_f : (row < 64) ? p.W_i0 : (row < 96) ? p.W_i1 : p.W_o;
    wg_lds[row * 65 + c] = W[(row & 31) * 64 + c];
  }
  if (tid < 32) {
    b_a1s[tid] = p.b_a1[tid];
    lng_s[tid] = p.ln_g[tid]; lnb_s[tid] = p.ln_b[tid];
    h_s[tid] = 0.f; qnf[tid] = 0.f; xcat[32 + tid] = 0.f; xcat[tid] = 0.f;
  }
  if (tid < 128) {
    const int g = tid >> 5, r = tid & 31;
    const float* bg = (g == 0) ? p.b_f : (g == 1) ? p.b_i0 : (g == 2) ? p.b_i1 : p.b_o;
    gb_s[tid] = bg[r];
  }
  if (tid < 8) c0own[tid] = p.wsf[WS_C0 + bid * 8 + tid];
  if (tid == 0) done_s = 0;

  v4f w0[8];  // W_a0 rows [8b,8b+8): thread = (row tid>>5, cols (tid&31)*32..+32)
  { const float* s = p.W_a0 + (size_t)(bid * 8 + (tid >> 5)) * ARD + (tid & 31) * 32;
    #pragma unroll
    for (int i = 0; i < 8; ++i) w0[i] = ((const v4f*)s)[i]; }
  v4f w3[32]; // W_a3 rows {tid, tid+256, tid+512, tid+768} in registers
  float b3[4];
  #pragma unroll
  for (int rr = 0; rr < 4; ++rr) {
    const float* s = p.W_a3 + (size_t)(tid + 256 * rr) * KD;
    #pragma unroll
    for (int i = 0; i < 8; ++i) w3[rr * 8 + i] = ((const v4f*)s)[i];
    b3[rr] = p.b_a3[tid + 256 * rr];
  }
  float kc[32];  // this thread's key column, register-resident
  { const int gcol = bid * 256 + tid;
    #pragma unroll
    for (int k = 0; k < 32; ++k) kc[k] = keys[(size_t)k * N_ENT + gcol]; }
  __syncthreads();

  auto produce = [&](unsigned tag) {
    const int seg = tid & 31, rl = tid >> 5;
    const float* a = &ar_s[seg * 33];
    float pa = 0.f;
    #pragma unroll
    for (int i = 0; i < 8; ++i) {
      v4f av = *(const v4f*)(a + 4 * i);
      pa += w0[i].x * av.x + w0[i].y * av.y + w0[i].z * av.z + w0[i].w * av.w;
    }
    #pragma unroll
    for (int m = 16; m; m >>= 1) pa += __shfl_xor(pa, m);
    if (seg == 0)
      st_pair(&ri0p[bid * 8 + rl], packf(fmaxf(pa + c0own[rl], 0.f), tag));
  };
  produce(1u);  // ri0 for step 0

  float v_reg = 0.f;
  for (int t = 0; t < steps; ++t) {
    const unsigned tg = (unsigned)(t + 1);

    // ==== Phase A1: wave0 polls ri0 (4 tags/lane), stages to LDS ====
    if (tid < 64) {
      ull u0, u1, u2, u3; int guard = 0;
      for (;;) {
        u0 = ld_pair(&ri0p[tid]);
        u1 = ld_pair(&ri0p[tid + 64]);
        u2 = ld_pair(&ri0p[tid + 128]);
        u3 = ld_pair(&ri0p[tid + 192]);
        if ((ptag(u0) == tg) && (ptag(u1) == tg) && (ptag(u2) == tg) && (ptag(u3) == tg)) break;
        if (++guard > (1 << 20)) break;  // failsafe: never hang
        __builtin_amdgcn_s_sleep(1);
      }
      ri0f[tid] = pvalf(u0); ri0f[tid + 64] = pvalf(u1);
      ri0f[tid + 128] = pvalf(u2); ri0f[tid + 192] = pvalf(u3);
    }
    bar_lds();
    const int act = (done_s == 0);

    // ==== Phase A2: wave0 solo LSTM chain (shfl, no cross-wave barriers) ====
    if (tid < 64) {
      // i1 = relu(W_a1 @ ri0 + b_a1): lanes l,l+32 split the 256-dot of row l&31
      {
        const int r = tid & 31, h = tid >> 5;
        const float* wrow = &w1_lds[r * 257 + h * 128];
        const float* xrow = &ri0f[h * 128];
        float p1 = 0.f;
        #pragma unroll
        for (int i = 0; i < 32; ++i) {
          v4f wv = *(const v4f*)(wrow + 4 * i);
          v4f xv = *(const v4f*)(xrow + 4 * i);
          p1 += wv.x * xv.x + wv.y * xv.y + wv.z * xv.z + wv.w * xv.w;
        }
        p1 += __shfl_xor(p1, 32);
        if (h == 0) xcat[r] = fmaxf(p1 + b_a1s[r], 0.f);
      }
      // gates: lane computes rows tid (f/i0-sig) and tid+64 (i1-tanh/o-sig)
      float ga, gb;
      {
        float pg0 = 0.f, pg1 = 0.f;
        #pragma unroll
        for (int i = 0; i < 16; ++i) {
          v4f xv = *(const v4f*)&xcat[4 * i];
          v4f wa = *(const v4f*)&wg_lds[tid * 65 + 4 * i];
          v4f wb = *(const v4f*)&wg_lds[(tid + 64) * 65 + 4 * i];
          pg0 += wa.x * xv.x + wa.y * xv.y + wa.z * xv.z + wa.w * xv.w;
          pg1 += wb.x * xv.x + wb.y * xv.y + wb.z * xv.z + wb.w * xv.w;
        }
        pg0 += gb_s[tid]; pg1 += gb_s[tid + 64];
        ga = 1.f / (1.f + __expf(-pg0));                                   // sig f / sig i0
        gb = (tid < 32) ? tanhf(pg1) : 1.f / (1.f + __expf(-pg1));         // tanh i1 / sig o
      }
      const float gbx = __shfl_xor(gb, 32);  // lanes<32: sig(o); lanes>=32: tanh(i1)
      // LN pass 1: lanes<32 a=sig(f); lanes>=32 a=sig(i0)*tanh(i1)
      float y;
      {
        const int k = tid & 31;
        const float a = (tid < 32) ? ga : ga * gbx;
        float s = a;
        #pragma unroll
        for (int m = 16; m; m >>= 1) s += __shfl_xor(s, m);
        const float mean = s * (1.f / 32.f);
        const float d = a - mean;
        float vv = d * d;
        #pragma unroll
        for (int m = 16; m; m >>= 1) vv += __shfl_xor(vv, m);
        vv *= (1.f / 32.f);
        y = d * rsqrtf(vv + 1e-5f) * lng_s[k] + lnb_s[k];
      }
      const float remv = __shfl_xor(y, 32);  // lanes<32 receive LN(remember)
      if (tid < 32) {
        // LN pass 2 (og) within lanes 0-31
        const float a = gbx;  // sig(o)
        float s = a;
        #pragma unroll
        for (int m = 16; m; m >>= 1) s += __shfl_xor(s, m);
        const float mean = s * (1.f / 32.f);
        const float d = a - mean;
        float vv = d * d;
        #pragma unroll
        for (int m = 16; m; m >>= 1) vv += __shfl_xor(vv, m);
        vv *= (1.f / 32.f);
        const float yo = d * rsqrtf(vv + 1e-5f) * lng_s[tid] + lnb_s[tid];
        const float nh = remv + y * h_s[tid];
        const float qv = tanhf(nh) * yo;
        qnf[tid] = qv;
        if (act) { h_s[tid] = nh; xcat[32 + tid] = qv; }
      }
    }
    bar_lds();

    // ==== Phase A3: sweep (all threads, register-resident key columns) ====
    {
      float dot = 0.f;
      #pragma unroll
      for (int k = 0; k < 32; ++k) dot += qnf[k] * kc[k];
      const float sig = 1.f / (1.f + __expf(-dot));
      const float v = __expf(__logf(sig) / 0.8f);  // sig^(1/TEMP)
      v_reg = v;
      float sv = v, mv = v;
      int mi = (bid << 8) + tid;
      #pragma unroll
      for (int m = 32; m; m >>= 1) {
        sv += __shfl_xor(sv, m);
        const float ov = __shfl_xor(mv, m);
        const int oi = __shfl_xor(mi, m);
        if (ov > mv || (ov == mv && oi < mi)) { mv = ov; mi = oi; }
      }
      const int wv = tid >> 6;
      if ((tid & 63) == 0) { reds[wv] = sv; rmaxs[wv] = mv; ridxs[wv] = mi; }
    }
    bar_lds();
    {  // ALL threads: block reduce; record + column ship issue together
      const float Sb = ((reds[0] + reds[1]) + reds[2]) + reds[3];
      float Mb = rmaxs[0]; int Ib = ridxs[0];
      #pragma unroll
      for (int i2 = 1; i2 < 4; ++i2)
        if (rmaxs[i2] > Mb || (rmaxs[i2] == Mb && ridxs[i2] < Ib)) { Mb = rmaxs[i2]; Ib = ridxs[i2]; }
      ull* rec = &partp[bid * 40];
      if (tid == 0) {
        st_pair(&rec[0], packf(Sb, tg));
        st_pair(&rec[1], packf(Mb, tg));
        st_pair(&rec[2], packi(Ib, tg));
      }
      if (((bid << 8) | tid) == Ib) {
        #pragma unroll
        for (int k = 0; k < 32; ++k) st_pair(&rec[3 + k], packf(kc[k], tg));
      }
    }

    // ==== Phase B: lanes 0-31 of wave0 poll records -> reduce -> cand poll ====
    if (tid < 32) {
      ull* rec = &partp[tid * 40];
      ull u0, u1, u2; int guard = 0;
      for (;;) {
        u0 = ld_pair(&rec[0]); u1 = ld_pair(&rec[1]); u2 = ld_pair(&rec[2]);
        if ((ptag(u0) == tg) && (ptag(u1) == tg) && (ptag(u2) == tg)) break;
        if (++guard > (1 << 20)) break;
        __builtin_amdgcn_s_sleep(1);
      }
      float s = pvalf(u0), m = pvalf(u1);
      int ii = (int)(unsigned)u2;
      #pragma unroll
      for (int mm = 16; mm; mm >>= 1) {
        s += __shfl_xor(s, mm);
        const float om = __shfl_xor(m, mm);
        const int oi = __shfl_xor(ii, mm);
        if (om > m || (om == m && oi < ii)) { m = om; ii = oi; }
      }
      // all 32 lanes hold global (S, M, I); poll the WINNER's cand only
      ull* crec = &partp[(ii >> 8) * 40 + 3];
      ull uc; guard = 0;
      for (;;) {
        uc = ld_pair(&crec[tid]);
        if (ptag(uc) == tg) break;
        if (++guard > (1 << 20)) break;
        __builtin_amdgcn_s_sleep(1);
      }
      const float kv = pvalf(uc);
      float mn = kv;
      #pragma unroll
      for (int mm = 16; mm; mm >>= 1) mn += __shfl_xor(mn, mm);
      mn *= (1.f / 32.f);
      const float cv = kv - mn;
      cent[tid] = cv;
      const unsigned long long bb = __ballot(cv != cv);
      if (tid == 0) {
        const int valid = (s != 0.f);
        const int nf = (bb == 0) ? 1 : 0;
        const unsigned mw = maskb[ii >> 5];
        const int hit = (act && valid && ((mw >> (ii & 31)) & 1)) ? 1 : 0;
        ssum_s = s;
        upd_s = (hit && nf) ? 1 : 0;
        if (hit) {
          maskb[ii >> 5] = mw & ~(1u << (ii & 31));
          selb[ii >> 5] |= (1u << (ii & 31));
          if (!nf) done_s = 1;
        }
      }
    }
    bar_lds();
    {  // row write for step t (never drained inside the loop)
      const float S = ssum_s;
      const float rowv = (act && (S != 0.f)) ? (v_reg / S) : 0.f;
      __builtin_nontemporal_store(rowv, p.out + (size_t)t * N_ENT + (bid << 8) + tid);
    }
    if (upd_s) {  // replicated ar update: 4 rows/thread, W_a3 in registers
      float cc[32];
      #pragma unroll
      for (int g = 0; g < 8; ++g) {
        v4f x = *(const v4f*)&cent[4 * g];
        cc[4 * g] = x.x; cc[4 * g + 1] = x.y; cc[4 * g + 2] = x.z; cc[4 * g + 3] = x.w;
      }
      float dl0 = b3[0], dl1 = b3[1], dl2 = b3[2], dl3 = b3[3];
      #pragma unroll
      for (int c = 0; c < 32; ++c) {
        const float cv = cc[c];
        dl0 += w3[c >> 2][c & 3] * cv;
        dl1 += w3[8 + (c >> 2)][c & 3] * cv;
        dl2 += w3[16 + (c >> 2)][c & 3] * cv;
        dl3 += w3[24 + (c >> 2)][c & 3] * cv;
      }
      if (dl0 > 0.f) ar_s[(tid >> 5) * 33 + (tid & 31)] += dl0;
      const int r1 = tid + 256, r2 = tid + 512, r3 = tid + 768;
      if (dl1 > 0.f) ar_s[(r1 >> 5) * 33 + (r1 & 31)] += dl1;
      if (dl2 > 0.f) ar_s[(r2 >> 5) * 33 + (r2 & 31)] += dl2;
      if (dl3 > 0.f) ar_s[(r3 >> 5) * 33 + (r3 & 31)] += dl3;
    }
    bar_lds();
    produce(tg + 1u);  // ri0 for step t+1
  }
  __syncthreads();

  // ==== epilogue: sel_out and ar_out (replicated state) ====
  if (bid == 0) {
    for (int i = tid; i < N_ENT; i += 256)
      p.out[NN + i] = ((selb[i >> 5] >> (i & 31)) & 1u) ? 1.f : 0.f;
  } else if (bid == 1) {
    for (int i = tid; i < ARD; i += 256)
      p.out[NN + N_ENT + i] = ar_s[(i >> 5) * 33 + (i & 31)];
  }
}

extern "C" void kernel_launch(void* const* d_in, const int* in_sizes, int n_in,
                              void* d_out, int out_size, void* d_ws, size_t ws_size,
                              hipStream_t stream) {
  (void)in_sizes; (void)n_in; (void)out_size; (void)ws_size;
  Params p;
  p.um    = (const float*)d_in[0];
  p.emask = (const float*)d_in[1];
  p.enc   = (const float*)d_in[2];
  p.arin  = (const float*)d_in[3];
  p.W_fe  = (const float*)d_in[4];
  p.b_fe  = (const float*)d_in[5];
  p.W_k   = (const float*)d_in[6];
  p.b_k   = (const float*)d_in[7];
  p.W_a0  = (const float*)d_in[8];
  p.b_a0  = (const float*)d_in[9];
  p.W_a1  = (const float*)d_in[10];
  p.b_a1  = (const float*)d_in[11];
  p.W_f   = (const float*)d_in[12];
  p.b_f   = (const float*)d_in[13];
  p.W_i0  = (const float*)d_in[14];
  p.b_i0  = (const float*)d_in[15];
  p.W_i1  = (const float*)d_in[16];
  p.b_i1  = (const float*)d_in[17];
  p.W_o   = (const float*)d_in[18];
  p.b_o   = (const float*)d_in[19];
  p.ln_g  = (const float*)d_in[20];
  p.ln_b  = (const float*)d_in[21];
  p.W_a3  = (const float*)d_in[22];
  p.b_a3  = (const float*)d_in[23];
  p.ct    = (const int*)d_in[24];
  p.out   = (float*)d_out;
  p.wsf   = (float*)d_ws;
  p.wsi   = (int*)d_ws;

  hipLaunchKernelGGL(k_init, dim3(256), dim3(256), 0, stream, p);
  hipLaunchKernelGGL(k_scan, dim3(NSCAN), dim3(256), 0, stream, p);
}